// Round 1
// 162.498 us; speedup vs baseline: 1.0093x; 1.0093x over previous
//
#include <hip/hip_runtime.h>
#include <hip/hip_bf16.h>
#include <stdint.h>

// LoRAExpert: out = ragged_dot(x, W, groups) + scale[a] * ((x @ A[a,e]) @ B[a,e])
// T=8192, D_IN=D_OUT=1024, E=8 (equal groups of 1024), A=4 adapters, R=16.
// Inputs fp32, output fp32. ws = 256 MiB.
//
// Round 6: 3 kernels, restructured:
//   k_prep : lora_A -> Aoct (scale folded); W/lora_B -> Boct oct-interleaved.
//            (x-pack removed -> 1344 blocks instead of 9536.)
//   k_xva  : reads x fp32 directly; converts to bf16 in-reg; writes xp[:, :1024]
//            AND stages the swizzled A-tile to LDS for the V=x@A MFMA in the
//            same pass (kills the xp round-trip k_vA used to do).
//            V (adapter-masked) -> xp[:, 1024:1088].
//   k_gemm : out = xp(K=1088) @ Boct[e]. NOW 1-D grid 512 with XCD-aware
//            swizzle: xcd = bid&7 owns a contiguous 8-row-panel x 8-ntile
//            chunk -> per-XCD working set ~4.4 MB (xp slice + one expert's
//            Boct) ~= L2-resident, instead of streaming all of xp through
//            every XCD's L2 (was ~142 MB LLC traffic).

#define T_TOK 8192
#define DIN   1024
#define DOUT  1024
#define NE    8
#define NA    4
#define RK    16
#define KEXT  1088      // 1024 + NA*RK
#define NOCT  136       // KEXT/8

typedef __attribute__((ext_vector_type(8))) short short8;
typedef __attribute__((ext_vector_type(4))) float f32x4;

__device__ __forceinline__ ushort f2bf(float f) {
  union { float f; uint32_t i; } v; v.f = f;
  uint32_t x = v.i;
  return (ushort)((x + 0x7fffu + ((x >> 16) & 1u)) >> 16);  // RNE
}

__device__ __forceinline__ void gload_lds16(const void* g, void* l) {
  __builtin_amdgcn_global_load_lds(
      (const __attribute__((address_space(1))) uint32_t*)g,
      (__attribute__((address_space(3))) uint32_t*)l,
      16, 0, 0);
}

__device__ __forceinline__ int expert_of_row(const int* __restrict__ gs, int row) {
  int cum = 0, e = 0;
#pragma unroll
  for (int i = 0; i < NE; ++i) { if (row >= cum) e = i; cum += gs[i]; }
  return e;
}

// ---- k_prep: weight packing only ----
// blocks [0, 256)       : lora_A -> Aoct[e][ko][c][8], scale folded
// blocks [256, 1280)    : W -> Boct[e][ko<128][n][8]
// blocks [1280, 1344)   : lora_B -> Boct[e][128+o][n][8]
__global__ __launch_bounds__(256) void k_prep(
    const float* __restrict__ weight,
    const float* __restrict__ lora_A, const float* __restrict__ lora_B,
    const float* __restrict__ lora_scaling,
    ushort* __restrict__ Aoct, ushort* __restrict__ Boct) {
  const int bid = blockIdx.x;
  const int tid = threadIdx.x;

  if (bid < 256) {                        // ---- pack lora_A ----
    int u = bid * 4 + (tid >> 6);         // 0..1023 = e*128+ko
    int e = u >> 7, ko = u & 127;
    int c = tid & 63;
    int a = c >> 4, r = c & 15;
    float s = lora_scaling[a];
    ushort o8[8];
#pragma unroll
    for (int j = 0; j < 8; ++j) {
      float v = lora_A[((size_t)(a * NE + e) * DIN + ko * 8 + j) * RK + r];
      o8[j] = f2bf(s * v);
    }
    *(uint4*)(Aoct + ((size_t)((e * 128 + ko) * 64 + c)) * 8) = *(const uint4*)o8;
  } else {                                // ---- pack Boct ----
    int e, ko;
    const float* srcbase;
    int stride;
    if (bid < 1280) {                     // W rows
      int u = bid - 256;                  // 0..1023
      e = u >> 7; ko = u & 127;
      srcbase = weight + (size_t)e * DIN * DOUT + (size_t)(ko * 8) * DOUT;
      stride = DOUT;
    } else {                              // lora_B rows
      int u = bid - 1280;                 // 0..63
      e = u >> 3; int o = u & 7; ko = 128 + o;
      srcbase = nullptr; stride = 0;
    }
    int n4 = tid * 4;
    float v[8][4];
    if (bid < 1280) {
#pragma unroll
      for (int j = 0; j < 8; ++j) {
        float4 q = *(const float4*)(srcbase + (size_t)j * stride + n4);
        v[j][0] = q.x; v[j][1] = q.y; v[j][2] = q.z; v[j][3] = q.w;
      }
    } else {
      int o = ko - 128;
#pragma unroll
      for (int j = 0; j < 8; ++j) {
        int kv = o * 8 + j;
        int a = kv >> 4, r = kv & 15;
        float4 q = *(const float4*)(lora_B + (size_t)((a * NE + e) * RK + r) * DOUT + n4);
        v[j][0] = q.x; v[j][1] = q.y; v[j][2] = q.z; v[j][3] = q.w;
      }
    }
    ushort* dst = Boct + ((size_t)(e * NOCT + ko) * DOUT + n4) * 8;
#pragma unroll
    for (int i = 0; i < 4; ++i) {
      ushort o8[8];
#pragma unroll
      for (int j = 0; j < 8; ++j) o8[j] = f2bf(v[j][i]);
      *(uint4*)(dst + i * 8) = *(const uint4*)o8;
    }
  }
}

// ---- k_xva: pack x -> xp[:, :1024] AND V = x @ Aoct[e] -> xp[:, 1024:1088] ----
// 128 blocks x 256 thr; tile 64 rows; BK=64 (16 iters).
// A-tile: x fp32 loaded to regs, converted, ds_write'd with the SAME XOR
// swizzle the fragment reads expect (LDS[row][q] = X[row][q^(row&7)]),
// and global-stored to xp in the same pass.
__global__ __launch_bounds__(256) void k_xva(
    const float* __restrict__ x, ushort* __restrict__ xp,
    const ushort* __restrict__ Aoct,
    const int* __restrict__ gs, const int* __restrict__ adapter_idx) {
  __shared__ ushort As2[64 * 64];     // 8 KB
  __shared__ ushort Bs2[8 * 64 * 8];  // 8 KB

  const int tid = threadIdx.x;
  const int lane = tid & 63;
  const int wave = tid >> 6;
  const int rows0 = blockIdx.x * 64;
  const int e = expert_of_row(gs, rows0);
  const ushort* aoct = Aoct + (size_t)e * 128 * 64 * 8;

  const int row = tid >> 2;           // 0..63 (4 threads per row)
  const int seg = tid & 3;            // 16 floats each
  const int r7 = row & 7;
  const int c0 = seg * 2;             // first 8-elem chunk this thread owns

  f32x4 acc[4];
#pragma unroll
  for (int ni = 0; ni < 4; ++ni) acc[ni] = (f32x4){0.f, 0.f, 0.f, 0.f};

  for (int kt = 0; kt < 16; ++kt) {
    // B: 2 async LDS loads/wave, one oct each (unchanged from k_vA)
#pragma unroll
    for (int rd = 0; rd < 2; ++rd) {
      int o = wave * 2 + rd;                    // local oct 0..7
      const ushort* src = aoct + ((size_t)(kt * 8 + o) * 64 + lane) * 8;
      gload_lds16(src, &Bs2[o * 64 * 8]);
    }

    // A: 16 fp32 from x -> 16 bf16 -> global xp + swizzled LDS
    const float* srcx = x + (size_t)(rows0 + row) * DIN + kt * 64 + seg * 16;
    float4 q0 = ((const float4*)srcx)[0];
    float4 q1 = ((const float4*)srcx)[1];
    float4 q2 = ((const float4*)srcx)[2];
    float4 q3 = ((const float4*)srcx)[3];
    ushort o16[16];
    o16[0] = f2bf(q0.x); o16[1] = f2bf(q0.y); o16[2] = f2bf(q0.z); o16[3] = f2bf(q0.w);
    o16[4] = f2bf(q1.x); o16[5] = f2bf(q1.y); o16[6] = f2bf(q1.z); o16[7] = f2bf(q1.w);
    o16[8]  = f2bf(q2.x); o16[9]  = f2bf(q2.y); o16[10] = f2bf(q2.z); o16[11] = f2bf(q2.w);
    o16[12] = f2bf(q3.x); o16[13] = f2bf(q3.y); o16[14] = f2bf(q3.z); o16[15] = f2bf(q3.w);

    ushort* dstg = xp + (size_t)(rows0 + row) * KEXT + kt * 64 + seg * 16;
    *(uint4*)(dstg)     = ((const uint4*)o16)[0];
    *(uint4*)(dstg + 8) = ((const uint4*)o16)[1];

    *(uint4*)&As2[row * 64 + ((c0 ^ r7) * 8)]       = ((const uint4*)o16)[0];
    *(uint4*)&As2[row * 64 + (((c0 + 1) ^ r7) * 8)] = ((const uint4*)o16)[1];

    __syncthreads();

    int m = wave * 16 + (lane & 15);
#pragma unroll
    for (int h = 0; h < 2; ++h) {
      int kblk = h * 4 + (lane >> 4);
      short8 af = *(const short8*)&As2[m * 64 + (kblk ^ (m & 7)) * 8];
#pragma unroll
      for (int ni = 0; ni < 4; ++ni) {
        short8 bfv = *(const short8*)&Bs2[(kblk * 64 + ni * 16 + (lane & 15)) * 8];
        acc[ni] = __builtin_amdgcn_mfma_f32_16x16x32_bf16(af, bfv, acc[ni], 0, 0, 0);
      }
    }
    __syncthreads();
  }

  // epilogue: col = ni*16+(lane&15) -> adapter slot is ni
#pragma unroll
  for (int i = 0; i < 4; ++i) {
    int grow = rows0 + wave * 16 + (lane >> 4) * 4 + i;
    int a_row = adapter_idx[grow];
#pragma unroll
    for (int ni = 0; ni < 4; ++ni) {
      float val = (a_row == ni) ? acc[ni][i] : 0.f;
      xp[(size_t)grow * KEXT + DIN + ni * 16 + (lane & 15)] = f2bf(val);
    }
  }
}

// ---- k_gemm: out[128x128] = xp(128 x 1088) @ Boct[e](1088 x 128) ----
// BK=64, 17 iters. A LDS XOR-swizzled. 1-D grid 512 with XCD swizzle:
// xcd = bid&7 -> contiguous chunk of 64 work units (8 row-panels x 8 ntiles,
// n fastest) so each XCD's L2 holds its xp slice (2.2 MB) + one expert's
// Boct (2.2 MB) instead of streaming all of xp.
__global__ __launch_bounds__(256) void k_gemm(
    const ushort* __restrict__ xp, const ushort* __restrict__ Boct,
    const int* __restrict__ gs, float* __restrict__ out) {
  __shared__ ushort As[128 * 64];      // 16 KB
  __shared__ ushort Bs[8 * 128 * 8];   // 16 KB

  const int tid = threadIdx.x;
  const int lane = tid & 63;
  const int wave = tid >> 6;
  const int wm = wave >> 1, wn = wave & 1;

  const int bid = blockIdx.x;                 // 0..511
  const int swz = (bid & 7) * 64 + (bid >> 3);  // bijective (512 % 8 == 0)
  const int row0 = (swz >> 3) * 128;
  const int n0 = (swz & 7) * 128;
  const int e = expert_of_row(gs, row0);
  const ushort* boct = Boct + (size_t)e * NOCT * DOUT * 8;

  f32x4 acc[4][4];
#pragma unroll
  for (int mi = 0; mi < 4; ++mi)
#pragma unroll
    for (int ni = 0; ni < 4; ++ni) acc[mi][ni] = (f32x4){0.f, 0.f, 0.f, 0.f};

  const int r8 = lane >> 3;
  const int c8s = (lane & 7) ^ r8;              // swizzled source chunk

  for (int kt = 0; kt < 17; ++kt) {
    // A: 4 calls/wave, 8 rows x 8 chunks each (swizzled)
#pragma unroll
    for (int rd = 0; rd < 4; ++rd) {
      int r = wave * 32 + rd * 8 + r8;
      const ushort* src = xp + (size_t)(row0 + r) * KEXT + kt * 64 + c8s * 8;
      gload_lds16(src, &As[(wave * 32 + rd * 8) * 64]);
    }
    // B: 4 calls/wave: unit = wave*4+rd -> oct o=unit>>1, half hf=unit&1
#pragma unroll
    for (int rd = 0; rd < 4; ++rd) {
      int u = wave * 4 + rd;
      int o = u >> 1, hf = u & 1;
      const ushort* src = boct + ((size_t)(kt * 8 + o) * DOUT + n0 + hf * 64 + lane) * 8;
      gload_lds16(src, &Bs[(o * 128 + hf * 64) * 8]);
    }
    __syncthreads();

#pragma unroll
    for (int h = 0; h < 2; ++h) {
      int kblk = h * 4 + (lane >> 4);
      short8 af[4], bfv[4];
#pragma unroll
      for (int mi = 0; mi < 4; ++mi) {
        int m = wm * 64 + mi * 16 + (lane & 15);
        af[mi] = *(const short8*)&As[m * 64 + (kblk ^ (m & 7)) * 8];
      }
#pragma unroll
      for (int ni = 0; ni < 4; ++ni) {
        int n = wn * 64 + ni * 16 + (lane & 15);
        bfv[ni] = *(const short8*)&Bs[(kblk * 128 + n) * 8];
      }
#pragma unroll
      for (int mi = 0; mi < 4; ++mi)
#pragma unroll
        for (int ni = 0; ni < 4; ++ni)
          acc[mi][ni] = __builtin_amdgcn_mfma_f32_16x16x32_bf16(
              af[mi], bfv[ni], acc[mi][ni], 0, 0, 0);
    }
    __syncthreads();
  }

  // epilogue: C layout col=lane&15, row=(lane>>4)*4+reg
#pragma unroll
  for (int mi = 0; mi < 4; ++mi) {
#pragma unroll
    for (int ni = 0; ni < 4; ++ni) {
      int col = n0 + wn * 64 + ni * 16 + (lane & 15);
#pragma unroll
      for (int i = 0; i < 4; ++i) {
        int r = row0 + wm * 64 + mi * 16 + (lane >> 4) * 4 + i;
        out[(size_t)r * DOUT + col] = acc[mi][ni][i];
      }
    }
  }
}

extern "C" void kernel_launch(void* const* d_in, const int* in_sizes, int n_in,
                              void* d_out, int out_size, void* d_ws, size_t ws_size,
                              hipStream_t stream) {
  const float* x            = (const float*)d_in[0];
  const float* weight       = (const float*)d_in[1];
  const float* lora_A       = (const float*)d_in[2];
  const float* lora_B       = (const float*)d_in[3];
  const float* lora_scaling = (const float*)d_in[4];
  const int*   group_sizes  = (const int*)d_in[5];
  const int*   adapter_idx  = (const int*)d_in[6];
  float* out = (float*)d_out;

  const size_t sz_xp    = (size_t)T_TOK * KEXT * 2;              // 17.8 MB
  const size_t sz_boct  = (size_t)NE * NOCT * DOUT * 8 * 2;      // 17.8 MB
  ushort* xp   = (ushort*)d_ws;
  ushort* boct = (ushort*)((char*)d_ws + sz_xp);
  ushort* aoct = (ushort*)((char*)d_ws + sz_xp + sz_boct);       // 1 MB

  k_prep<<<1344, 256, 0, stream>>>(weight, lora_A, lora_B, lora_scaling,
                                   aoct, boct);
  k_xva<<<T_TOK / 64, 256, 0, stream>>>(x, xp, aoct, group_sizes, adapter_idx);
  k_gemm<<<512, 256, 0, stream>>>(xp, boct, group_sizes, out);
}

// Round 3
// 159.204 us; speedup vs baseline: 1.0302x; 1.0207x over previous
//
#include <hip/hip_runtime.h>
#include <hip/hip_bf16.h>
#include <stdint.h>

// LoRAExpert: out = ragged_dot(x, W, groups) + scale[a] * ((x @ A[a,e]) @ B[a,e])
// T=8192, D_IN=D_OUT=1024, E=8 (equal groups of 1024), A=4 adapters, R=16.
// Inputs fp32, output fp32. ws = 256 MiB.
//
// Round 8 (= round 7 resubmit; container failed twice, source audited clean):
//   k_prepA : lora_A -> Aoct (scale folded). 256 blocks, ~2 us. Only this
//             tiny piece sits on k_main's critical path.
//   k_main  : blocks [0,512)    : xva -- 16-row tiles: reads x fp32,
//                                 packs bf16 -> xp[:, :1024], V = x@Aoct[e]
//                                 (adapter-masked) -> xp[:, 1024:1088].
//                                 512 blocks = 2/CU, 8 waves/CU.
//             blocks [512,1600) : W/lora_B -> Boct oct-interleaved pack.
//                                 No dependency on xva; BW-bound pack blocks
//                                 backfill CUs while xva blocks wait on HBM.
//   k_gemm  : out = xp(K=1088) @ Boct[e]. m97-structure 128x128, BK=64,
//             XOR-swizzled A LDS, gload_lds w16, XCD-aware 1-D swizzle.

#define T_TOK 8192
#define DIN   1024
#define DOUT  1024
#define NE    8
#define NA    4
#define RK    16
#define KEXT  1088      // 1024 + NA*RK
#define NOCT  136       // KEXT/8

typedef __attribute__((ext_vector_type(8))) short short8;
typedef __attribute__((ext_vector_type(4))) float f32x4;

__device__ __forceinline__ ushort f2bf(float f) {
  union { float f; uint32_t i; } v; v.f = f;
  uint32_t x = v.i;
  return (ushort)((x + 0x7fffu + ((x >> 16) & 1u)) >> 16);  // RNE
}

__device__ __forceinline__ void gload_lds16(const void* g, void* l) {
  __builtin_amdgcn_global_load_lds(
      (const __attribute__((address_space(1))) uint32_t*)g,
      (__attribute__((address_space(3))) uint32_t*)l,
      16, 0, 0);
}

__device__ __forceinline__ int expert_of_row(const int* __restrict__ gs, int row) {
  int cum = 0, e = 0;
#pragma unroll
  for (int i = 0; i < NE; ++i) { if (row >= cum) e = i; cum += gs[i]; }
  return e;
}

// ---- k_prepA: lora_A -> Aoct[e][ko][c][8], scale folded. 256 blocks. ----
__global__ __launch_bounds__(256) void k_prepA(
    const float* __restrict__ lora_A, const float* __restrict__ lora_scaling,
    ushort* __restrict__ Aoct) {
  const int bid = blockIdx.x;
  const int tid = threadIdx.x;
  int u = bid * 4 + (tid >> 6);         // 0..1023 = e*128+ko
  int e = u >> 7, ko = u & 127;
  int c = tid & 63;
  int a = c >> 4, r = c & 15;
  float s = lora_scaling[a];
  ushort o8[8];
#pragma unroll
  for (int j = 0; j < 8; ++j) {
    float v = lora_A[((size_t)(a * NE + e) * DIN + ko * 8 + j) * RK + r];
    o8[j] = f2bf(s * v);
  }
  *(uint4*)(Aoct + ((size_t)((e * 128 + ko) * 64 + c)) * 8) = *(const uint4*)o8;
}

// ---- k_main ----
// blocks [0,512)     : xva, 16-row tiles
// blocks [512,1536)  : W -> Boct[e][ko<128][n][8]
// blocks [1536,1600) : lora_B -> Boct[e][128+o][n][8]
__global__ __launch_bounds__(256) void k_main(
    const float* __restrict__ x, ushort* __restrict__ xp,
    const ushort* __restrict__ Aoct,
    const float* __restrict__ weight, const float* __restrict__ lora_B,
    ushort* __restrict__ Boct,
    const int* __restrict__ gs, const int* __restrict__ adapter_idx) {
  __shared__ ushort As2[16 * 64];     // 2 KB
  __shared__ ushort Bs2[8 * 64 * 8];  // 8 KB

  const int bid = blockIdx.x;
  const int tid = threadIdx.x;

  if (bid < 512) {
    // ======== xva: pack x rows [bid*16, +16) and compute V ========
    const int lane = tid & 63;
    const int wave = tid >> 6;
    const int rows0 = bid * 16;
    const int e = expert_of_row(gs, rows0);
    const ushort* aoct = Aoct + (size_t)e * 128 * 64 * 8;

    const int row = tid >> 4;           // 0..15
    const int seg = tid & 15;           // 4 floats each
    const int r7 = row & 7;

    f32x4 acc = (f32x4){0.f, 0.f, 0.f, 0.f};

    for (int kt = 0; kt < 16; ++kt) {
      // B: 2 async LDS loads/wave, one oct each
#pragma unroll
      for (int rd = 0; rd < 2; ++rd) {
        int o = wave * 2 + rd;                    // local oct 0..7
        const ushort* src = aoct + ((size_t)(kt * 8 + o) * 64 + lane) * 8;
        gload_lds16(src, &Bs2[o * 64 * 8]);
      }

      // A: 4 fp32 from x -> 4 bf16 -> global xp + swizzled LDS half-chunk
      const float* srcx = x + (size_t)(rows0 + row) * DIN + kt * 64 + seg * 4;
      float4 q = *(const float4*)srcx;
      ushort4 b;
      b.x = f2bf(q.x); b.y = f2bf(q.y); b.z = f2bf(q.z); b.w = f2bf(q.w);
      *(ushort4*)(xp + (size_t)(rows0 + row) * KEXT + kt * 64 + seg * 4) = b;
      int ch = (seg >> 1) ^ r7;                   // swizzled chunk index
      *(ushort4*)&As2[row * 64 + ch * 8 + (seg & 1) * 4] = b;

      __syncthreads();

      int m = lane & 15;
#pragma unroll
      for (int h = 0; h < 2; ++h) {
        int kblk = h * 4 + (lane >> 4);
        short8 af = *(const short8*)&As2[m * 64 + (kblk ^ (m & 7)) * 8];
        short8 bfv = *(const short8*)&Bs2[(kblk * 64 + wave * 16 + m) * 8];
        acc = __builtin_amdgcn_mfma_f32_16x16x32_bf16(af, bfv, acc, 0, 0, 0);
      }
      __syncthreads();
    }

    // epilogue: this wave owns V cols [wave*16, +16) -> adapter slot = wave
#pragma unroll
    for (int i = 0; i < 4; ++i) {
      int grow = rows0 + (lane >> 4) * 4 + i;
      int a_row = adapter_idx[grow];
      float val = (a_row == wave) ? acc[i] : 0.f;
      xp[(size_t)grow * KEXT + DIN + wave * 16 + (lane & 15)] = f2bf(val);
    }
  } else {
    // ======== Boct pack ========
    int e, ko;
    const float* srcbase = nullptr;
    if (bid < 1536) {                     // W rows
      int u = bid - 512;                  // 0..1023
      e = u >> 7; ko = u & 127;
      srcbase = weight + (size_t)e * DIN * DOUT + (size_t)(ko * 8) * DOUT;
    } else {                              // lora_B rows
      int u = bid - 1536;                 // 0..63
      e = u >> 3; int o = u & 7; ko = 128 + o;
    }
    int n4 = tid * 4;
    float v[8][4];
    if (bid < 1536) {
#pragma unroll
      for (int j = 0; j < 8; ++j) {
        float4 q = *(const float4*)(srcbase + (size_t)j * DOUT + n4);
        v[j][0] = q.x; v[j][1] = q.y; v[j][2] = q.z; v[j][3] = q.w;
      }
    } else {
      int o = ko - 128;
#pragma unroll
      for (int j = 0; j < 8; ++j) {
        int kv = o * 8 + j;
        int a = kv >> 4, r = kv & 15;
        float4 q = *(const float4*)(lora_B + (size_t)((a * NE + e) * RK + r) * DOUT + n4);
        v[j][0] = q.x; v[j][1] = q.y; v[j][2] = q.z; v[j][3] = q.w;
      }
    }
    ushort* dst = Boct + ((size_t)(e * NOCT + ko) * DOUT + n4) * 8;
#pragma unroll
    for (int i = 0; i < 4; ++i) {
      ushort o8[8];
#pragma unroll
      for (int j = 0; j < 8; ++j) o8[j] = f2bf(v[j][i]);
      *(uint4*)(dst + i * 8) = *(const uint4*)o8;
    }
  }
}

// ---- k_gemm: out[128x128] = xp(128 x 1088) @ Boct[e](1088 x 128) ----
// BK=64, 17 iters. A LDS XOR-swizzled. 1-D grid 512 with XCD swizzle.
__global__ __launch_bounds__(256) void k_gemm(
    const ushort* __restrict__ xp, const ushort* __restrict__ Boct,
    const int* __restrict__ gs, float* __restrict__ out) {
  __shared__ ushort As[128 * 64];      // 16 KB
  __shared__ ushort Bs[8 * 128 * 8];   // 16 KB

  const int tid = threadIdx.x;
  const int lane = tid & 63;
  const int wave = tid >> 6;
  const int wm = wave >> 1, wn = wave & 1;

  const int bid = blockIdx.x;                 // 0..511
  const int swz = (bid & 7) * 64 + (bid >> 3);  // bijective (512 % 8 == 0)
  const int row0 = (swz >> 3) * 128;
  const int n0 = (swz & 7) * 128;
  const int e = expert_of_row(gs, row0);
  const ushort* boct = Boct + (size_t)e * NOCT * DOUT * 8;

  f32x4 acc[4][4];
#pragma unroll
  for (int mi = 0; mi < 4; ++mi)
#pragma unroll
    for (int ni = 0; ni < 4; ++ni) acc[mi][ni] = (f32x4){0.f, 0.f, 0.f, 0.f};

  const int r8 = lane >> 3;
  const int c8s = (lane & 7) ^ r8;              // swizzled source chunk

  for (int kt = 0; kt < 17; ++kt) {
    // A: 4 calls/wave, 8 rows x 8 chunks each (swizzled)
#pragma unroll
    for (int rd = 0; rd < 4; ++rd) {
      int r = wave * 32 + rd * 8 + r8;
      const ushort* src = xp + (size_t)(row0 + r) * KEXT + kt * 64 + c8s * 8;
      gload_lds16(src, &As[(wave * 32 + rd * 8) * 64]);
    }
    // B: 4 calls/wave: unit = wave*4+rd -> oct o=unit>>1, half hf=unit&1
#pragma unroll
    for (int rd = 0; rd < 4; ++rd) {
      int u = wave * 4 + rd;
      int o = u >> 1, hf = u & 1;
      const ushort* src = boct + ((size_t)(kt * 8 + o) * DOUT + n0 + hf * 64 + lane) * 8;
      gload_lds16(src, &Bs[(o * 128 + hf * 64) * 8]);
    }
    __syncthreads();

#pragma unroll
    for (int h = 0; h < 2; ++h) {
      int kblk = h * 4 + (lane >> 4);
      short8 af[4], bfv[4];
#pragma unroll
      for (int mi = 0; mi < 4; ++mi) {
        int m = wm * 64 + mi * 16 + (lane & 15);
        af[mi] = *(const short8*)&As[m * 64 + (kblk ^ (m & 7)) * 8];
      }
#pragma unroll
      for (int ni = 0; ni < 4; ++ni) {
        int n = wn * 64 + ni * 16 + (lane & 15);
        bfv[ni] = *(const short8*)&Bs[(kblk * 128 + n) * 8];
      }
#pragma unroll
      for (int mi = 0; mi < 4; ++mi)
#pragma unroll
        for (int ni = 0; ni < 4; ++ni)
          acc[mi][ni] = __builtin_amdgcn_mfma_f32_16x16x32_bf16(
              af[mi], bfv[ni], acc[mi][ni], 0, 0, 0);
    }
    __syncthreads();
  }

  // epilogue: C layout col=lane&15, row=(lane>>4)*4+reg
#pragma unroll
  for (int mi = 0; mi < 4; ++mi) {
#pragma unroll
    for (int ni = 0; ni < 4; ++ni) {
      int col = n0 + wn * 64 + ni * 16 + (lane & 15);
#pragma unroll
      for (int i = 0; i < 4; ++i) {
        int r = row0 + wm * 64 + mi * 16 + (lane >> 4) * 4 + i;
        out[(size_t)r * DOUT + col] = acc[mi][ni][i];
      }
    }
  }
}

extern "C" void kernel_launch(void* const* d_in, const int* in_sizes, int n_in,
                              void* d_out, int out_size, void* d_ws, size_t ws_size,
                              hipStream_t stream) {
  const float* x            = (const float*)d_in[0];
  const float* weight       = (const float*)d_in[1];
  const float* lora_A       = (const float*)d_in[2];
  const float* lora_B       = (const float*)d_in[3];
  const float* lora_scaling = (const float*)d_in[4];
  const int*   group_sizes  = (const int*)d_in[5];
  const int*   adapter_idx  = (const int*)d_in[6];
  float* out = (float*)d_out;

  const size_t sz_xp    = (size_t)T_TOK * KEXT * 2;              // 17.8 MB
  const size_t sz_boct  = (size_t)NE * NOCT * DOUT * 8 * 2;      // 17.8 MB
  ushort* xp   = (ushort*)d_ws;
  ushort* boct = (ushort*)((char*)d_ws + sz_xp);
  ushort* aoct = (ushort*)((char*)d_ws + sz_xp + sz_boct);       // 1 MB

  k_prepA<<<256, 256, 0, stream>>>(lora_A, lora_scaling, aoct);
  k_main<<<1600, 256, 0, stream>>>(x, xp, aoct, weight, lora_B, boct,
                                   group_sizes, adapter_idx);
  k_gemm<<<512, 256, 0, stream>>>(xp, boct, group_sizes, out);
}

// Round 4
// 156.278 us; speedup vs baseline: 1.0494x; 1.0187x over previous
//
#include <hip/hip_runtime.h>
#include <hip/hip_bf16.h>
#include <stdint.h>

// LoRAExpert: out = ragged_dot(x, W, groups) + scale[a] * ((x @ A[a,e]) @ B[a,e])
// T=8192, D_IN=D_OUT=1024, E=8 (equal groups of 1024), A=4 adapters, R=16.
// Inputs fp32, output fp32. ws = 256 MiB.
//
// Round 9: de-serialize xva. R8 counters: k_main 40.7us @ 12% HBM, 0.9% MFMA,
// 28.8% occ -> latency-bound on 16 barrier-drain iterations. Now 4 K-tiles
// per stage (As2 8KB + Bs2 32KB = 40KB LDS), 4 iterations x 2 barriers
// instead of 16 x 2 -> 4x fewer serialized load-drains; x read is 64B/thread
// contiguous (was 16B).
//   k_prepA : lora_A -> Aoct (scale folded). 256 blocks.
//   k_main  : blocks [0,512)    : xva, 16-row tiles, 4-tile K-batching.
//             blocks [512,1600) : W/lora_B -> Boct pack (unchanged).
//   k_gemm  : unchanged m97-structure 128x128, BK=64, XCD swizzle.

#define T_TOK 8192
#define DIN   1024
#define DOUT  1024
#define NE    8
#define NA    4
#define RK    16
#define KEXT  1088      // 1024 + NA*RK
#define NOCT  136       // KEXT/8

typedef __attribute__((ext_vector_type(8))) short short8;
typedef __attribute__((ext_vector_type(4))) float f32x4;

__device__ __forceinline__ ushort f2bf(float f) {
  union { float f; uint32_t i; } v; v.f = f;
  uint32_t x = v.i;
  return (ushort)((x + 0x7fffu + ((x >> 16) & 1u)) >> 16);  // RNE
}

__device__ __forceinline__ void gload_lds16(const void* g, void* l) {
  __builtin_amdgcn_global_load_lds(
      (const __attribute__((address_space(1))) uint32_t*)g,
      (__attribute__((address_space(3))) uint32_t*)l,
      16, 0, 0);
}

__device__ __forceinline__ int expert_of_row(const int* __restrict__ gs, int row) {
  int cum = 0, e = 0;
#pragma unroll
  for (int i = 0; i < NE; ++i) { if (row >= cum) e = i; cum += gs[i]; }
  return e;
}

// ---- k_prepA: lora_A -> Aoct[e][ko][c][8], scale folded. 256 blocks. ----
__global__ __launch_bounds__(256) void k_prepA(
    const float* __restrict__ lora_A, const float* __restrict__ lora_scaling,
    ushort* __restrict__ Aoct) {
  const int bid = blockIdx.x;
  const int tid = threadIdx.x;
  int u = bid * 4 + (tid >> 6);         // 0..1023 = e*128+ko
  int e = u >> 7, ko = u & 127;
  int c = tid & 63;
  int a = c >> 4, r = c & 15;
  float s = lora_scaling[a];
  ushort o8[8];
#pragma unroll
  for (int j = 0; j < 8; ++j) {
    float v = lora_A[((size_t)(a * NE + e) * DIN + ko * 8 + j) * RK + r];
    o8[j] = f2bf(s * v);
  }
  *(uint4*)(Aoct + ((size_t)((e * 128 + ko) * 64 + c)) * 8) = *(const uint4*)o8;
}

// ---- k_main ----
// blocks [0,512)     : xva, 16-row tiles, 4 K-tiles per stage
// blocks [512,1536)  : W -> Boct[e][ko<128][n][8]
// blocks [1536,1600) : lora_B -> Boct[e][128+o][n][8]
__global__ __launch_bounds__(256) void k_main(
    const float* __restrict__ x, ushort* __restrict__ xp,
    const ushort* __restrict__ Aoct,
    const float* __restrict__ weight, const float* __restrict__ lora_B,
    ushort* __restrict__ Boct,
    const int* __restrict__ gs, const int* __restrict__ adapter_idx) {
  __shared__ ushort As2[4 * 16 * 64];     // 8 KB  (4 K-tiles x 16 rows x 64)
  __shared__ ushort Bs2[4 * 8 * 64 * 8];  // 32 KB (4 K-tiles x 8 octs)

  const int bid = blockIdx.x;
  const int tid = threadIdx.x;

  if (bid < 512) {
    // ======== xva: pack x rows [bid*16, +16) and compute V ========
    const int lane = tid & 63;
    const int wave = tid >> 6;
    const int rows0 = bid * 16;
    const int e = expert_of_row(gs, rows0);
    const ushort* aoct = Aoct + (size_t)e * 128 * 64 * 8;

    const int row = tid >> 4;           // 0..15
    const int seg = tid & 15;           // 16 floats each (64 B contiguous)
    const int r7 = row & 7;
    const int t4 = seg >> 2;            // K-tile within the 4-batch
    const int c0 = (seg & 3) * 2;       // first 8-elem chunk within tile

    f32x4 acc = (f32x4){0.f, 0.f, 0.f, 0.f};

    for (int it = 0; it < 4; ++it) {
      // B: 8 async LDS loads/wave (4 tiles x 2 octs each)
#pragma unroll
      for (int i = 0; i < 8; ++i) {
        int t = i >> 1;
        int o = wave * 2 + (i & 1);               // oct 0..7 across 4 waves
        const ushort* src = aoct + ((size_t)((it * 4 + t) * 8 + o) * 64 + lane) * 8;
        gload_lds16(src, &Bs2[((t * 8 + o) * 64) * 8]);
      }

      // A: 16 fp32 (64 B contiguous) -> 16 bf16 -> global xp + swizzled LDS
      const float* srcx = x + (size_t)(rows0 + row) * DIN + it * 256 + seg * 16;
      float4 q0 = ((const float4*)srcx)[0];
      float4 q1 = ((const float4*)srcx)[1];
      float4 q2 = ((const float4*)srcx)[2];
      float4 q3 = ((const float4*)srcx)[3];
      ushort o16[16];
      o16[0]  = f2bf(q0.x); o16[1]  = f2bf(q0.y); o16[2]  = f2bf(q0.z); o16[3]  = f2bf(q0.w);
      o16[4]  = f2bf(q1.x); o16[5]  = f2bf(q1.y); o16[6]  = f2bf(q1.z); o16[7]  = f2bf(q1.w);
      o16[8]  = f2bf(q2.x); o16[9]  = f2bf(q2.y); o16[10] = f2bf(q2.z); o16[11] = f2bf(q2.w);
      o16[12] = f2bf(q3.x); o16[13] = f2bf(q3.y); o16[14] = f2bf(q3.z); o16[15] = f2bf(q3.w);

      ushort* dstg = xp + (size_t)(rows0 + row) * KEXT + it * 256 + seg * 16;
      *(uint4*)(dstg)     = ((const uint4*)o16)[0];
      *(uint4*)(dstg + 8) = ((const uint4*)o16)[1];

      *(uint4*)&As2[(t4 * 16 + row) * 64 + ((c0 ^ r7) * 8)]       = ((const uint4*)o16)[0];
      *(uint4*)&As2[(t4 * 16 + row) * 64 + (((c0 + 1) ^ r7) * 8)] = ((const uint4*)o16)[1];

      __syncthreads();

      int m = lane & 15;
#pragma unroll
      for (int t = 0; t < 4; ++t) {
#pragma unroll
        for (int h = 0; h < 2; ++h) {
          int kblk = h * 4 + (lane >> 4);
          short8 af = *(const short8*)&As2[(t * 16 + m) * 64 + (kblk ^ (m & 7)) * 8];
          short8 bfv = *(const short8*)&Bs2[((t * 8 + kblk) * 64 + wave * 16 + m) * 8];
          acc = __builtin_amdgcn_mfma_f32_16x16x32_bf16(af, bfv, acc, 0, 0, 0);
        }
      }
      __syncthreads();
    }

    // epilogue: this wave owns V cols [wave*16, +16) -> adapter slot = wave
#pragma unroll
    for (int i = 0; i < 4; ++i) {
      int grow = rows0 + (lane >> 4) * 4 + i;
      int a_row = adapter_idx[grow];
      float val = (a_row == wave) ? acc[i] : 0.f;
      xp[(size_t)grow * KEXT + DIN + wave * 16 + (lane & 15)] = f2bf(val);
    }
  } else {
    // ======== Boct pack ========
    int e, ko;
    const float* srcbase = nullptr;
    if (bid < 1536) {                     // W rows
      int u = bid - 512;                  // 0..1023
      e = u >> 7; ko = u & 127;
      srcbase = weight + (size_t)e * DIN * DOUT + (size_t)(ko * 8) * DOUT;
    } else {                              // lora_B rows
      int u = bid - 1536;                 // 0..63
      e = u >> 3; int o = u & 7; ko = 128 + o;
    }
    int n4 = tid * 4;
    float v[8][4];
    if (bid < 1536) {
#pragma unroll
      for (int j = 0; j < 8; ++j) {
        float4 q = *(const float4*)(srcbase + (size_t)j * DOUT + n4);
        v[j][0] = q.x; v[j][1] = q.y; v[j][2] = q.z; v[j][3] = q.w;
      }
    } else {
      int o = ko - 128;
#pragma unroll
      for (int j = 0; j < 8; ++j) {
        int kv = o * 8 + j;
        int a = kv >> 4, r = kv & 15;
        float4 q = *(const float4*)(lora_B + (size_t)((a * NE + e) * RK + r) * DOUT + n4);
        v[j][0] = q.x; v[j][1] = q.y; v[j][2] = q.z; v[j][3] = q.w;
      }
    }
    ushort* dst = Boct + ((size_t)(e * NOCT + ko) * DOUT + n4) * 8;
#pragma unroll
    for (int i = 0; i < 4; ++i) {
      ushort o8[8];
#pragma unroll
      for (int j = 0; j < 8; ++j) o8[j] = f2bf(v[j][i]);
      *(uint4*)(dst + i * 8) = *(const uint4*)o8;
    }
  }
}

// ---- k_gemm: out[128x128] = xp(128 x 1088) @ Boct[e](1088 x 128) ----
// BK=64, 17 iters. A LDS XOR-swizzled. 1-D grid 512 with XCD swizzle.
__global__ __launch_bounds__(256) void k_gemm(
    const ushort* __restrict__ xp, const ushort* __restrict__ Boct,
    const int* __restrict__ gs, float* __restrict__ out) {
  __shared__ ushort As[128 * 64];      // 16 KB
  __shared__ ushort Bs[8 * 128 * 8];   // 16 KB

  const int tid = threadIdx.x;
  const int lane = tid & 63;
  const int wave = tid >> 6;
  const int wm = wave >> 1, wn = wave & 1;

  const int bid = blockIdx.x;                 // 0..511
  const int swz = (bid & 7) * 64 + (bid >> 3);  // bijective (512 % 8 == 0)
  const int row0 = (swz >> 3) * 128;
  const int n0 = (swz & 7) * 128;
  const int e = expert_of_row(gs, row0);
  const ushort* boct = Boct + (size_t)e * NOCT * DOUT * 8;

  f32x4 acc[4][4];
#pragma unroll
  for (int mi = 0; mi < 4; ++mi)
#pragma unroll
    for (int ni = 0; ni < 4; ++ni) acc[mi][ni] = (f32x4){0.f, 0.f, 0.f, 0.f};

  const int r8 = lane >> 3;
  const int c8s = (lane & 7) ^ r8;              // swizzled source chunk

  for (int kt = 0; kt < 17; ++kt) {
    // A: 4 calls/wave, 8 rows x 8 chunks each (swizzled)
#pragma unroll
    for (int rd = 0; rd < 4; ++rd) {
      int r = wave * 32 + rd * 8 + r8;
      const ushort* src = xp + (size_t)(row0 + r) * KEXT + kt * 64 + c8s * 8;
      gload_lds16(src, &As[(wave * 32 + rd * 8) * 64]);
    }
    // B: 4 calls/wave: unit = wave*4+rd -> oct o=unit>>1, half hf=unit&1
#pragma unroll
    for (int rd = 0; rd < 4; ++rd) {
      int u = wave * 4 + rd;
      int o = u >> 1, hf = u & 1;
      const ushort* src = boct + ((size_t)(kt * 8 + o) * DOUT + n0 + hf * 64 + lane) * 8;
      gload_lds16(src, &Bs[(o * 128 + hf * 64) * 8]);
    }
    __syncthreads();

#pragma unroll
    for (int h = 0; h < 2; ++h) {
      int kblk = h * 4 + (lane >> 4);
      short8 af[4], bfv[4];
#pragma unroll
      for (int mi = 0; mi < 4; ++mi) {
        int m = wm * 64 + mi * 16 + (lane & 15);
        af[mi] = *(const short8*)&As[m * 64 + (kblk ^ (m & 7)) * 8];
      }
#pragma unroll
      for (int ni = 0; ni < 4; ++ni) {
        int n = wn * 64 + ni * 16 + (lane & 15);
        bfv[ni] = *(const short8*)&Bs[(kblk * 128 + n) * 8];
      }
#pragma unroll
      for (int mi = 0; mi < 4; ++mi)
#pragma unroll
        for (int ni = 0; ni < 4; ++ni)
          acc[mi][ni] = __builtin_amdgcn_mfma_f32_16x16x32_bf16(
              af[mi], bfv[ni], acc[mi][ni], 0, 0, 0);
    }
    __syncthreads();
  }

  // epilogue: C layout col=lane&15, row=(lane>>4)*4+reg
#pragma unroll
  for (int mi = 0; mi < 4; ++mi) {
#pragma unroll
    for (int ni = 0; ni < 4; ++ni) {
      int col = n0 + wn * 64 + ni * 16 + (lane & 15);
#pragma unroll
      for (int i = 0; i < 4; ++i) {
        int r = row0 + wm * 64 + mi * 16 + (lane >> 4) * 4 + i;
        out[(size_t)r * DOUT + col] = acc[mi][ni][i];
      }
    }
  }
}

extern "C" void kernel_launch(void* const* d_in, const int* in_sizes, int n_in,
                              void* d_out, int out_size, void* d_ws, size_t ws_size,
                              hipStream_t stream) {
  const float* x            = (const float*)d_in[0];
  const float* weight       = (const float*)d_in[1];
  const float* lora_A       = (const float*)d_in[2];
  const float* lora_B       = (const float*)d_in[3];
  const float* lora_scaling = (const float*)d_in[4];
  const int*   group_sizes  = (const int*)d_in[5];
  const int*   adapter_idx  = (const int*)d_in[6];
  float* out = (float*)d_out;

  const size_t sz_xp    = (size_t)T_TOK * KEXT * 2;              // 17.8 MB
  const size_t sz_boct  = (size_t)NE * NOCT * DOUT * 8 * 2;      // 17.8 MB
  ushort* xp   = (ushort*)d_ws;
  ushort* boct = (ushort*)((char*)d_ws + sz_xp);
  ushort* aoct = (ushort*)((char*)d_ws + sz_xp + sz_boct);       // 1 MB

  k_prepA<<<256, 256, 0, stream>>>(lora_A, lora_scaling, aoct);
  k_main<<<1600, 256, 0, stream>>>(x, xp, aoct, weight, lora_B, boct,
                                   group_sizes, adapter_idx);
  k_gemm<<<512, 256, 0, stream>>>(xp, boct, group_sizes, out);
}